// Round 17
// baseline (103.277 us; speedup 1.0000x reference)
//
#include <hip/hip_runtime.h>

#define N_NODES 50000
#define D 128
#define NC 256                 // edge chunks (= count/scatter grid = #CUs)
#define SCANB 196              // scanAB blocks (196*256 = 50176 >= N)
#define CONV_NB 1563           // ceil(1600000/1024) convert blocks

typedef short bf16x8 __attribute__((ext_vector_type(8)));
typedef float f32x4 __attribute__((ext_vector_type(4)));
typedef float f32x2 __attribute__((ext_vector_type(2)));
typedef unsigned char uchar;

__device__ __forceinline__ ushort f2bf(float f) {
    uint u = __float_as_uint(f);
    u += 0x7FFF + ((u >> 16) & 1);     // round-to-nearest-even
    return (ushort)(u >> 16);
}

// unpack 8 fp8 (uint2) and accumulate into a[0..8)
__device__ __forceinline__ void addrow8(uint2 q, float* a) {
    f32x2 p;
    p = __builtin_amdgcn_cvt_pk_f32_fp8(q.x, false); a[0] += p.x; a[1] += p.y;
    p = __builtin_amdgcn_cvt_pk_f32_fp8(q.x, true);  a[2] += p.x; a[3] += p.y;
    p = __builtin_amdgcn_cvt_pk_f32_fp8(q.y, false); a[4] += p.x; a[5] += p.y;
    p = __builtin_amdgcn_cvt_pk_f32_fp8(q.y, true);  a[6] += p.x; a[7] += p.y;
}

// ====== hetero pass: blocks [0,NC) = chunk histogram; rest = convert ========
__global__ __launch_bounds__(1024) void fused_count_convert(
        const float* __restrict__ x, const float* __restrict__ Wl,
        const float* __restrict__ Wr, const int* __restrict__ dst,
        ushort* __restrict__ x_bf, int* __restrict__ x_fp8,
        ushort* __restrict__ Btf, uchar* __restrict__ cum,
        int E, int chunk) {
    const int b = blockIdx.x;
    const int t = threadIdx.x;
    if (b < NC) {
        // ---- histogram (4x uchar packed per uint; per-chunk count <= ~6) ----
        __shared__ uint cnt[N_NODES / 4];     // 12500 uints = 50 KB
        for (int k = t; k < N_NODES / 4; k += 1024) cnt[k] = 0;
        __syncthreads();
        const int e0 = b * chunk;
        const int e1 = min(E, e0 + chunk);
        for (int e = e0 + t; e < e1; e += 1024) {
            int d = dst[e];
            atomicAdd(&cnt[d >> 2], 1u << ((d & 3) << 3));
        }
        __syncthreads();
        uint* pu = (uint*)(cum + (size_t)b * N_NODES);
        for (int k = t; k < N_NODES / 4; k += 1024) pu[k] = cnt[k];
    } else {
        // ---- convert: x->bf16 + x->fp8 (interleaved rows) + frag-major B ----
        const int i = (b - NC) * 1024 + t;
        if (i < (N_NODES * D) / 4) {
            float4 v = ((const float4*)x)[i];
            ushort4 o;
            o.x = f2bf(v.x); o.y = f2bf(v.y); o.z = f2bf(v.z); o.w = f2bf(v.w);
            ((ushort4*)x_bf)[i] = o;
            int p = __builtin_amdgcn_cvt_pk_fp8_f32(v.x, v.y, 0, false);
            p = __builtin_amdgcn_cvt_pk_fp8_f32(v.z, v.w, p, true);
            x_fp8[i] = p;
        }
        // Btf[((ks*8+nf)*64 + l)*8 + j] = W[k][col]
        if (i < 32768) {
            int j  = i & 7;
            int l  = (i >> 3) & 63;
            int nf = (i >> 9) & 7;
            int ks = (i >> 12) & 7;
            int lr = l & 15, kb = l >> 4;
            int col  = nf * 16 + lr;
            int kloc = (ks & 3) * 32 + kb * 8 + j;
            const float* W = (ks < 4) ? Wl : Wr;
            Btf[i] = f2bf(W[kloc * D + col]);
        }
    }
}

// ====== pass B: in-place chunk-prefix (uchar) + block-LOCAL exclusive scan ==
__global__ __launch_bounds__(256) void scanAB_kernel(uchar* __restrict__ cum,
                                                     int* __restrict__ offsets,
                                                     int* __restrict__ blocksums) {
    __shared__ int wsums[4];
    __shared__ int wbase[4];
    const int t = threadIdx.x;
    const int lane = t & 63;
    const int wid = t >> 6;
    const int n = blockIdx.x * 256 + t;

    int s = 0;
    if (n < N_NODES) {
        #pragma unroll 4
        for (int c = 0; c < NC; ++c) {
            int v = (int)cum[(size_t)c * N_NODES + n];
            cum[(size_t)c * N_NODES + n] = (uchar)s;
            s += v;
        }
    }
    int sc = s;
    #pragma unroll
    for (int off = 1; off < 64; off <<= 1) {
        int u = __shfl_up(sc, off);
        if (lane >= off) sc += u;
    }
    if (lane == 63) wsums[wid] = sc;
    __syncthreads();
    if (t == 0) {
        int c = 0;
        #pragma unroll
        for (int w = 0; w < 4; ++w) { int tmp = wsums[w]; wbase[w] = c; c += tmp; }
        blocksums[blockIdx.x] = c;
    }
    __syncthreads();
    if (n < N_NODES) offsets[n] = wbase[wid] + sc - s;
}

// ====== pass C: scatter into CSR (uchar LDS ranks + inline base scan) =======
__global__ __launch_bounds__(1024) void scatterC_kernel(const int* __restrict__ src,
                                                        const int* __restrict__ dst,
                                                        const int* __restrict__ offsets,
                                                        const int* __restrict__ blocksums,
                                                        const uchar* __restrict__ cum,
                                                        ushort* __restrict__ sorted_src,
                                                        int E, int chunk) {
    __shared__ uint cnt[N_NODES / 4];     // 50 KB
    __shared__ int base[SCANB];
    const int t = threadIdx.x;
    const int b = blockIdx.x;
    for (int k = t; k < N_NODES / 4; k += 1024) cnt[k] = 0;
    if (t < SCANB) base[t] = blocksums[t];
    __syncthreads();
    if (t == 0) {
        int run = 0;
        for (int k = 0; k < SCANB; ++k) { int v = base[k]; base[k] = run; run += v; }
    }
    __syncthreads();
    const uchar* cb = cum + (size_t)b * N_NODES;
    const int e0 = b * chunk;
    const int e1 = min(E, e0 + chunk);
    for (int e = e0 + t; e < e1; e += 1024) {
        int d = dst[e];
        uint prev = atomicAdd(&cnt[d >> 2], 1u << ((d & 3) << 3));
        int lrank = (int)((prev >> ((d & 3) << 3)) & 0xFFu);
        int pos = offsets[d] + base[d >> 8] + (int)cb[d] + lrank;
        sorted_src[pos] = (ushort)src[e];
    }
}

// ====== one-pass full-row aggregation (fp8 gather) -> bf16 ==================
// 16 lanes/node, one uint2 (8 fp8) of the 128B row each; 8-edge unroll
// -> 8 gathers in flight per lane; each node visited ONCE (no plane passes).
// 16 nodes per 256-thread block -> 3125 blocks; deg-divergence = max of 4
// nodes per wave.
__global__ __launch_bounds__(256) void aggregate_fp8(const int* __restrict__ x_fp8,
                                                     const ushort* __restrict__ sorted_src,
                                                     const int* __restrict__ offsets,
                                                     const int* __restrict__ blocksums,
                                                     ushort* __restrict__ agg_bf, int E) {
    __shared__ int base[SCANB];
    const int b = blockIdx.x;
    const int t = threadIdx.x;

    if (t < SCANB) base[t] = blocksums[t];
    __syncthreads();
    if (t == 0) {
        int run = 0;
        for (int k = 0; k < SCANB; ++k) { int v = base[k]; base[k] = run; run += v; }
    }
    __syncthreads();

    const int g = t >> 4;                 // node slot 0..15
    const int j = t & 15;                 // uint2 chunk within 128B row
    const int node = b * 16 + g;
    if (node >= N_NODES) return;
    const int s = offsets[node] + base[node >> 8];
    const int np = node + 1;
    const int e = (np < N_NODES) ? (offsets[np] + base[np >> 8]) : E;

    const uint2* xq = (const uint2*)x_fp8;   // row = 16 uint2 (128 fp8)

    float a[8];
    #pragma unroll
    for (int k = 0; k < 8; ++k) a[k] = 0.0f;

    int p = s;
    for (; p + 8 <= e; p += 8) {
        int s0 = sorted_src[p + 0];
        int s1 = sorted_src[p + 1];
        int s2 = sorted_src[p + 2];
        int s3 = sorted_src[p + 3];
        int s4 = sorted_src[p + 4];
        int s5 = sorted_src[p + 5];
        int s6 = sorted_src[p + 6];
        int s7 = sorted_src[p + 7];
        uint2 q0 = xq[s0 * 16 + j];
        uint2 q1 = xq[s1 * 16 + j];
        uint2 q2 = xq[s2 * 16 + j];
        uint2 q3 = xq[s3 * 16 + j];
        uint2 q4 = xq[s4 * 16 + j];
        uint2 q5 = xq[s5 * 16 + j];
        uint2 q6 = xq[s6 * 16 + j];
        uint2 q7 = xq[s7 * 16 + j];
        addrow8(q0, a); addrow8(q1, a); addrow8(q2, a); addrow8(q3, a);
        addrow8(q4, a); addrow8(q5, a); addrow8(q6, a); addrow8(q7, a);
    }
    for (; p < e; ++p) {
        int s0 = sorted_src[p];
        uint2 q0 = xq[s0 * 16 + j];
        addrow8(q0, a);
    }

    const int dcnt = e - s;
    const float scale = (dcnt > 0) ? (1.0f / (float)dcnt) : 0.0f;
    ushort tmp[8];
    #pragma unroll
    for (int k = 0; k < 8; ++k) tmp[k] = f2bf(a[k] * scale);
    *(int4*)&agg_bf[node * D + j * 8] = *(int4*)tmp;
}

// ---------------- GEMM, 0 LDS, 0 barriers: out=relu([agg|x]@[Wl;Wr]+b) -----
__global__ __launch_bounds__(256) void gemm_direct(const ushort* __restrict__ agg_bf,
                                                   const ushort* __restrict__ x_bf,
                                                   const ushort* __restrict__ Btf,
                                                   const float* __restrict__ bias,
                                                   float* __restrict__ out) {
    const int t = threadIdx.x;
    const int w = t >> 6;
    const int l = t & 63;
    const int lr = l & 15;
    const int kb = l >> 4;
    const int n0 = blockIdx.x * 64;

    int r = n0 + w * 16 + lr;
    if (r >= N_NODES) r = N_NODES - 1;

    f32x4 acc[8] = {};

    #pragma unroll
    for (int ks = 0; ks < 8; ++ks) {
        bf16x8 af = (ks < 4)
            ? *(const bf16x8*)&agg_bf[r * D + ks * 32 + kb * 8]
            : *(const bf16x8*)&x_bf[r * D + (ks - 4) * 32 + kb * 8];
        const ushort* bp = Btf + (size_t)(ks * 8 * 64 + l) * 8;
        #pragma unroll
        for (int nf = 0; nf < 8; ++nf) {
            bf16x8 bfr = *(const bf16x8*)&bp[nf * 64 * 8];
            acc[nf] = __builtin_amdgcn_mfma_f32_16x16x32_bf16(af, bfr, acc[nf], 0, 0, 0);
        }
    }

    // C/D layout: col = lane&15, row = (lane>>4)*4 + i
    #pragma unroll
    for (int nf = 0; nf < 8; ++nf) {
        const int col = nf * 16 + lr;
        const float bb = bias[col];
        #pragma unroll
        for (int i = 0; i < 4; ++i) {
            int row = n0 + w * 16 + kb * 4 + i;
            if (row < N_NODES)
                out[row * D + col] = fmaxf(acc[nf][i] + bb, 0.0f);
        }
    }
}

// ============================================================================
extern "C" void kernel_launch(void* const* d_in, const int* in_sizes, int n_in,
                              void* d_out, int out_size, void* d_ws, size_t ws_size,
                              hipStream_t stream) {
    const float* x  = (const float*)d_in[0];
    const int*   ei = (const int*)d_in[1];
    const float* Wl = (const float*)d_in[2];
    const float* Wr = (const float*)d_in[3];
    const float* b  = (const float*)d_in[4];
    float* out = (float*)d_out;

    const int E = in_sizes[1] / 2;
    const int* src = ei;
    const int* dst = ei + E;
    const int chunk = (E + NC - 1) / NC;

    // workspace layout (16B-aligned sections)
    char* wsp = (char*)d_ws;
    int*    offsets   = (int*)(wsp + 0);               // 50176 ints (local scan)
    int*    blocksums = (int*)(wsp + 200704);          // 256 ints
    ushort* sorted    = (ushort*)(wsp + 201728);       // 800016 ushorts
    uchar*  cum       = (uchar*)(wsp + 1801760);       // 256*50000 uchars (12.8MB)
    ushort* x_bf      = (ushort*)(wsp + 14601760);     // 6,400,000 ushorts
    int*    x_fp8     = (int*)(wsp + 27401760);        // 1,600,000 ints (interleaved)
    ushort* agg_bf    = (ushort*)(wsp + 33801760);     // 6,400,000 ushorts
    ushort* Btf       = (ushort*)(wsp + 46601760);     // 32768 ushorts
    // total = 46,667,296 bytes

    fused_count_convert<<<NC + CONV_NB, 1024, 0, stream>>>(
        x, Wl, Wr, dst, x_bf, x_fp8, Btf, cum, E, chunk);
    scanAB_kernel<<<SCANB, 256, 0, stream>>>(cum, offsets, blocksums);
    scatterC_kernel<<<NC, 1024, 0, stream>>>(src, dst, offsets, blocksums, cum,
                                             sorted, E, chunk);
    aggregate_fp8<<<(N_NODES + 15) / 16, 256, 0, stream>>>(
        x_fp8, sorted, offsets, blocksums, agg_bf, E);
    gemm_direct<<<(N_NODES + 63) / 64, 256, 0, stream>>>(agg_bf, x_bf, Btf, b, out);
}

// Round 18
// 98.447 us; speedup vs baseline: 1.0491x; 1.0491x over previous
//
#include <hip/hip_runtime.h>

#define N_NODES 50000
#define D 128
#define NC 256                 // edge chunks (= count/scatter grid = #CUs)
#define SCANB 196              // scanAB blocks (196*256 = 50176 >= N)
#define CONV_NB 1563           // ceil(1600000/1024) convert blocks

typedef short bf16x8 __attribute__((ext_vector_type(8)));
typedef float f32x4 __attribute__((ext_vector_type(4)));
typedef float f32x2 __attribute__((ext_vector_type(2)));
typedef unsigned char uchar;

__device__ __forceinline__ ushort f2bf(float f) {
    uint u = __float_as_uint(f);
    u += 0x7FFF + ((u >> 16) & 1);     // round-to-nearest-even
    return (ushort)(u >> 16);
}

// unpack 8 fp8 (uint2) and accumulate into a[0..8)
__device__ __forceinline__ void addrow8(uint2 q, float* a) {
    f32x2 p;
    p = __builtin_amdgcn_cvt_pk_f32_fp8(q.x, false); a[0] += p.x; a[1] += p.y;
    p = __builtin_amdgcn_cvt_pk_f32_fp8(q.x, true);  a[2] += p.x; a[3] += p.y;
    p = __builtin_amdgcn_cvt_pk_f32_fp8(q.y, false); a[4] += p.x; a[5] += p.y;
    p = __builtin_amdgcn_cvt_pk_f32_fp8(q.y, true);  a[6] += p.x; a[7] += p.y;
}

// ====== parallel exclusive scan of blocksums[0..SCANB) into LDS base ========
// ~300 cycles (vs ~23,500 for the old t==0 serial loop). Works for any
// blockDim >= 256. Must be called by ALL threads (contains barriers).
__device__ __forceinline__ void scan_base(const int* __restrict__ blocksums,
                                          int* base, int* wtot) {
    const int t = threadIdx.x;
    const int lane = t & 63;
    const int wid = t >> 6;
    int v = (t < SCANB) ? blocksums[t] : 0;
    int sc = v;
    #pragma unroll
    for (int off = 1; off < 64; off <<= 1) {
        int u = __shfl_up(sc, off);
        if (lane >= off) sc += u;
    }
    if (t < 256 && lane == 63) wtot[wid] = sc;   // totals of waves 0..3
    __syncthreads();
    if (t < SCANB) {
        int wb = 0;
        #pragma unroll
        for (int w2 = 0; w2 < 4; ++w2) if (w2 < wid) wb += wtot[w2];
        base[t] = wb + sc - v;                   // exclusive prefix
    }
    __syncthreads();
}

// ====== hetero pass: blocks [0,NC) = chunk histogram; rest = convert ========
__global__ __launch_bounds__(1024) void fused_count_convert(
        const float* __restrict__ x, const float* __restrict__ Wl,
        const float* __restrict__ Wr, const int* __restrict__ dst,
        ushort* __restrict__ x_bf, int* __restrict__ x_fp8,
        ushort* __restrict__ Btf, uchar* __restrict__ cum,
        int E, int chunk) {
    const int b = blockIdx.x;
    const int t = threadIdx.x;
    if (b < NC) {
        // ---- histogram (4x uchar packed per uint; per-chunk count <= ~6) ----
        __shared__ uint cnt[N_NODES / 4];     // 12500 uints = 50 KB
        for (int k = t; k < N_NODES / 4; k += 1024) cnt[k] = 0;
        __syncthreads();
        const int e0 = b * chunk;
        const int e1 = min(E, e0 + chunk);
        for (int e = e0 + t; e < e1; e += 1024) {
            int d = dst[e];
            atomicAdd(&cnt[d >> 2], 1u << ((d & 3) << 3));
        }
        __syncthreads();
        uint* pu = (uint*)(cum + (size_t)b * N_NODES);
        for (int k = t; k < N_NODES / 4; k += 1024) pu[k] = cnt[k];
    } else {
        // ---- convert: x->bf16 + x->fp8 (interleaved rows) + frag-major B ----
        const int i = (b - NC) * 1024 + t;
        if (i < (N_NODES * D) / 4) {
            float4 v = ((const float4*)x)[i];
            ushort4 o;
            o.x = f2bf(v.x); o.y = f2bf(v.y); o.z = f2bf(v.z); o.w = f2bf(v.w);
            ((ushort4*)x_bf)[i] = o;
            int p = __builtin_amdgcn_cvt_pk_fp8_f32(v.x, v.y, 0, false);
            p = __builtin_amdgcn_cvt_pk_fp8_f32(v.z, v.w, p, true);
            x_fp8[i] = p;
        }
        // Btf[((ks*8+nf)*64 + l)*8 + j] = W[k][col]
        if (i < 32768) {
            int j  = i & 7;
            int l  = (i >> 3) & 63;
            int nf = (i >> 9) & 7;
            int ks = (i >> 12) & 7;
            int lr = l & 15, kb = l >> 4;
            int col  = nf * 16 + lr;
            int kloc = (ks & 3) * 32 + kb * 8 + j;
            const float* W = (ks < 4) ? Wl : Wr;
            Btf[i] = f2bf(W[kloc * D + col]);
        }
    }
}

// ====== pass B: in-place chunk-prefix (uchar) + block-LOCAL exclusive scan ==
__global__ __launch_bounds__(256) void scanAB_kernel(uchar* __restrict__ cum,
                                                     int* __restrict__ offsets,
                                                     int* __restrict__ blocksums) {
    __shared__ int wsums[4];
    __shared__ int wbase[4];
    const int t = threadIdx.x;
    const int lane = t & 63;
    const int wid = t >> 6;
    const int n = blockIdx.x * 256 + t;

    int s = 0;
    if (n < N_NODES) {
        #pragma unroll 4
        for (int c = 0; c < NC; ++c) {
            int v = (int)cum[(size_t)c * N_NODES + n];
            cum[(size_t)c * N_NODES + n] = (uchar)s;
            s += v;
        }
    }
    int sc = s;
    #pragma unroll
    for (int off = 1; off < 64; off <<= 1) {
        int u = __shfl_up(sc, off);
        if (lane >= off) sc += u;
    }
    if (lane == 63) wsums[wid] = sc;
    __syncthreads();
    if (t == 0) {
        int c = 0;
        #pragma unroll
        for (int w = 0; w < 4; ++w) { int tmp = wsums[w]; wbase[w] = c; c += tmp; }
        blocksums[blockIdx.x] = c;
    }
    __syncthreads();
    if (n < N_NODES) offsets[n] = wbase[wid] + sc - s;
}

// ====== pass C: scatter into CSR (uchar LDS ranks + PARALLEL base scan) =====
__global__ __launch_bounds__(1024) void scatterC_kernel(const int* __restrict__ src,
                                                        const int* __restrict__ dst,
                                                        const int* __restrict__ offsets,
                                                        const int* __restrict__ blocksums,
                                                        const uchar* __restrict__ cum,
                                                        ushort* __restrict__ sorted_src,
                                                        int E, int chunk) {
    __shared__ uint cnt[N_NODES / 4];     // 50 KB
    __shared__ int base[SCANB];
    __shared__ int wtot[4];
    const int t = threadIdx.x;
    const int b = blockIdx.x;
    for (int k = t; k < N_NODES / 4; k += 1024) cnt[k] = 0;
    scan_base(blocksums, base, wtot);     // includes barriers
    const uchar* cb = cum + (size_t)b * N_NODES;
    const int e0 = b * chunk;
    const int e1 = min(E, e0 + chunk);
    for (int e = e0 + t; e < e1; e += 1024) {
        int d = dst[e];
        uint prev = atomicAdd(&cnt[d >> 2], 1u << ((d & 3) << 3));
        int lrank = (int)((prev >> ((d & 3) << 3)) & 0xFFu);
        int pos = offsets[d] + base[d >> 8] + (int)cb[d] + lrank;
        sorted_src[pos] = (ushort)src[e];
    }
}

// ====== one-pass full-row aggregation (fp8 gather) -> bf16 ==================
// 16 lanes/node, one uint2 (8 fp8) of the 128B row each; 8-edge unroll;
// PARALLEL base scan prologue (~300cy vs ~23500cy serial).
__global__ __launch_bounds__(256) void aggregate_fp8(const int* __restrict__ x_fp8,
                                                     const ushort* __restrict__ sorted_src,
                                                     const int* __restrict__ offsets,
                                                     const int* __restrict__ blocksums,
                                                     ushort* __restrict__ agg_bf, int E) {
    __shared__ int base[SCANB];
    __shared__ int wtot[4];
    const int b = blockIdx.x;
    const int t = threadIdx.x;

    scan_base(blocksums, base, wtot);     // includes barriers

    const int g = t >> 4;                 // node slot 0..15
    const int j = t & 15;                 // uint2 chunk within 128B row
    const int node = b * 16 + g;
    if (node >= N_NODES) return;
    const int s = offsets[node] + base[node >> 8];
    const int np = node + 1;
    const int e = (np < N_NODES) ? (offsets[np] + base[np >> 8]) : E;

    const uint2* xq = (const uint2*)x_fp8;   // row = 16 uint2 (128 fp8)

    float a[8];
    #pragma unroll
    for (int k = 0; k < 8; ++k) a[k] = 0.0f;

    int p = s;
    for (; p + 8 <= e; p += 8) {
        int s0 = sorted_src[p + 0];
        int s1 = sorted_src[p + 1];
        int s2 = sorted_src[p + 2];
        int s3 = sorted_src[p + 3];
        int s4 = sorted_src[p + 4];
        int s5 = sorted_src[p + 5];
        int s6 = sorted_src[p + 6];
        int s7 = sorted_src[p + 7];
        uint2 q0 = xq[s0 * 16 + j];
        uint2 q1 = xq[s1 * 16 + j];
        uint2 q2 = xq[s2 * 16 + j];
        uint2 q3 = xq[s3 * 16 + j];
        uint2 q4 = xq[s4 * 16 + j];
        uint2 q5 = xq[s5 * 16 + j];
        uint2 q6 = xq[s6 * 16 + j];
        uint2 q7 = xq[s7 * 16 + j];
        addrow8(q0, a); addrow8(q1, a); addrow8(q2, a); addrow8(q3, a);
        addrow8(q4, a); addrow8(q5, a); addrow8(q6, a); addrow8(q7, a);
    }
    for (; p < e; ++p) {
        int s0 = sorted_src[p];
        uint2 q0 = xq[s0 * 16 + j];
        addrow8(q0, a);
    }

    const int dcnt = e - s;
    const float scale = (dcnt > 0) ? (1.0f / (float)dcnt) : 0.0f;
    ushort tmp[8];
    #pragma unroll
    for (int k = 0; k < 8; ++k) tmp[k] = f2bf(a[k] * scale);
    *(int4*)&agg_bf[node * D + j * 8] = *(int4*)tmp;
}

// ---------------- GEMM, 0 LDS, 0 barriers: out=relu([agg|x]@[Wl;Wr]+b) -----
__global__ __launch_bounds__(256) void gemm_direct(const ushort* __restrict__ agg_bf,
                                                   const ushort* __restrict__ x_bf,
                                                   const ushort* __restrict__ Btf,
                                                   const float* __restrict__ bias,
                                                   float* __restrict__ out) {
    const int t = threadIdx.x;
    const int w = t >> 6;
    const int l = t & 63;
    const int lr = l & 15;
    const int kb = l >> 4;
    const int n0 = blockIdx.x * 64;

    int r = n0 + w * 16 + lr;
    if (r >= N_NODES) r = N_NODES - 1;

    f32x4 acc[8] = {};

    #pragma unroll
    for (int ks = 0; ks < 8; ++ks) {
        bf16x8 af = (ks < 4)
            ? *(const bf16x8*)&agg_bf[r * D + ks * 32 + kb * 8]
            : *(const bf16x8*)&x_bf[r * D + (ks - 4) * 32 + kb * 8];
        const ushort* bp = Btf + (size_t)(ks * 8 * 64 + l) * 8;
        #pragma unroll
        for (int nf = 0; nf < 8; ++nf) {
            bf16x8 bfr = *(const bf16x8*)&bp[nf * 64 * 8];
            acc[nf] = __builtin_amdgcn_mfma_f32_16x16x32_bf16(af, bfr, acc[nf], 0, 0, 0);
        }
    }

    // C/D layout: col = lane&15, row = (lane>>4)*4 + i
    #pragma unroll
    for (int nf = 0; nf < 8; ++nf) {
        const int col = nf * 16 + lr;
        const float bb = bias[col];
        #pragma unroll
        for (int i = 0; i < 4; ++i) {
            int row = n0 + w * 16 + kb * 4 + i;
            if (row < N_NODES)
                out[row * D + col] = fmaxf(acc[nf][i] + bb, 0.0f);
        }
    }
}

// ============================================================================
extern "C" void kernel_launch(void* const* d_in, const int* in_sizes, int n_in,
                              void* d_out, int out_size, void* d_ws, size_t ws_size,
                              hipStream_t stream) {
    const float* x  = (const float*)d_in[0];
    const int*   ei = (const int*)d_in[1];
    const float* Wl = (const float*)d_in[2];
    const float* Wr = (const float*)d_in[3];
    const float* b  = (const float*)d_in[4];
    float* out = (float*)d_out;

    const int E = in_sizes[1] / 2;
    const int* src = ei;
    const int* dst = ei + E;
    const int chunk = (E + NC - 1) / NC;

    // workspace layout (16B-aligned sections)
    char* wsp = (char*)d_ws;
    int*    offsets   = (int*)(wsp + 0);               // 50176 ints (local scan)
    int*    blocksums = (int*)(wsp + 200704);          // 256 ints
    ushort* sorted    = (ushort*)(wsp + 201728);       // 800016 ushorts
    uchar*  cum       = (uchar*)(wsp + 1801760);       // 256*50000 uchars (12.8MB)
    ushort* x_bf      = (ushort*)(wsp + 14601760);     // 6,400,000 ushorts
    int*    x_fp8     = (int*)(wsp + 27401760);        // 1,600,000 ints (interleaved)
    ushort* agg_bf    = (ushort*)(wsp + 33801760);     // 6,400,000 ushorts
    ushort* Btf       = (ushort*)(wsp + 46601760);     // 32768 ushorts
    // total = 46,667,296 bytes

    fused_count_convert<<<NC + CONV_NB, 1024, 0, stream>>>(
        x, Wl, Wr, dst, x_bf, x_fp8, Btf, cum, E, chunk);
    scanAB_kernel<<<SCANB, 256, 0, stream>>>(cum, offsets, blocksums);
    scatterC_kernel<<<NC, 1024, 0, stream>>>(src, dst, offsets, blocksums, cum,
                                             sorted, E, chunk);
    aggregate_fp8<<<(N_NODES + 15) / 16, 256, 0, stream>>>(
        x_fp8, sorted, offsets, blocksums, agg_bf, E);
    gemm_direct<<<(N_NODES + 63) / 64, 256, 0, stream>>>(agg_bf, x_bf, Btf, b, out);
}

// Round 19
// 96.219 us; speedup vs baseline: 1.0734x; 1.0232x over previous
//
#include <hip/hip_runtime.h>

#define N_NODES 50000
#define D 128
#define NC 256                 // edge chunks (= count/scatter grid = #CUs)
#define SCANB 196              // scanAB blocks (196*256 = 50176 >= N)
#define CONV_NB 1563           // ceil(1600000/1024) convert blocks
#define ZROW 50000             // reserved all-zero row in x_fp8

typedef short bf16x8 __attribute__((ext_vector_type(8)));
typedef float f32x4 __attribute__((ext_vector_type(4)));
typedef float f32x2 __attribute__((ext_vector_type(2)));
typedef unsigned char uchar;

__device__ __forceinline__ ushort f2bf(float f) {
    uint u = __float_as_uint(f);
    u += 0x7FFF + ((u >> 16) & 1);     // round-to-nearest-even
    return (ushort)(u >> 16);
}

// unpack 8 fp8 (uint2) and accumulate into a[0..8)
__device__ __forceinline__ void addrow8(uint2 q, float* a) {
    f32x2 p;
    p = __builtin_amdgcn_cvt_pk_f32_fp8(q.x, false); a[0] += p.x; a[1] += p.y;
    p = __builtin_amdgcn_cvt_pk_f32_fp8(q.x, true);  a[2] += p.x; a[3] += p.y;
    p = __builtin_amdgcn_cvt_pk_f32_fp8(q.y, false); a[4] += p.x; a[5] += p.y;
    p = __builtin_amdgcn_cvt_pk_f32_fp8(q.y, true);  a[6] += p.x; a[7] += p.y;
}

// ====== parallel exclusive scan of blocksums[0..SCANB) into LDS base ========
__device__ __forceinline__ void scan_base(const int* __restrict__ blocksums,
                                          int* base, int* wtot) {
    const int t = threadIdx.x;
    const int lane = t & 63;
    const int wid = t >> 6;
    int v = (t < SCANB) ? blocksums[t] : 0;
    int sc = v;
    #pragma unroll
    for (int off = 1; off < 64; off <<= 1) {
        int u = __shfl_up(sc, off);
        if (lane >= off) sc += u;
    }
    if (t < 256 && lane == 63) wtot[wid] = sc;
    __syncthreads();
    if (t < SCANB) {
        int wb = 0;
        #pragma unroll
        for (int w2 = 0; w2 < 4; ++w2) if (w2 < wid) wb += wtot[w2];
        base[t] = wb + sc - v;
    }
    __syncthreads();
}

// ====== hetero pass: blocks [0,NC) = chunk histogram; rest = convert ========
// Convert blocks also: prefill sorted[] with ZROW pattern, zero x_fp8 row ZROW.
__global__ __launch_bounds__(1024) void fused_count_convert(
        const float* __restrict__ x, const float* __restrict__ Wl,
        const float* __restrict__ Wr, const int* __restrict__ dst,
        ushort* __restrict__ x_bf, int* __restrict__ x_fp8,
        ushort* __restrict__ Btf, uchar* __restrict__ cum,
        uint* __restrict__ sorted_u32,
        int E, int chunk) {
    const int b = blockIdx.x;
    const int t = threadIdx.x;
    if (b < NC) {
        // ---- histogram (4x uchar packed per uint; per-chunk count <= ~6) ----
        __shared__ uint cnt[N_NODES / 4];     // 12500 uints = 50 KB
        for (int k = t; k < N_NODES / 4; k += 1024) cnt[k] = 0;
        __syncthreads();
        const int e0 = b * chunk;
        const int e1 = min(E, e0 + chunk);
        for (int e = e0 + t; e < e1; e += 1024) {
            int d = dst[e];
            atomicAdd(&cnt[d >> 2], 1u << ((d & 3) << 3));
        }
        __syncthreads();
        uint* pu = (uint*)(cum + (size_t)b * N_NODES);
        for (int k = t; k < N_NODES / 4; k += 1024) pu[k] = cnt[k];
    } else {
        // ---- convert: x->bf16 + x->fp8 (interleaved rows) + frag-major B ----
        const int i = (b - NC) * 1024 + t;
        if (i < (N_NODES * D) / 4) {
            float4 v = ((const float4*)x)[i];
            ushort4 o;
            o.x = f2bf(v.x); o.y = f2bf(v.y); o.z = f2bf(v.z); o.w = f2bf(v.w);
            ((ushort4*)x_bf)[i] = o;
            int p = __builtin_amdgcn_cvt_pk_fp8_f32(v.x, v.y, 0, false);
            p = __builtin_amdgcn_cvt_pk_fp8_f32(v.z, v.w, p, true);
            x_fp8[i] = p;
        }
        // prefill sorted with ZROW pattern (1,200,016 ushorts = 600,008 uints)
        if (i < 600008) sorted_u32[i] = 0xC350C350u;   // 0xC350 = 50000
        // zero row ZROW of x_fp8 (32 ints)
        if (i < 32) x_fp8[ZROW * 32 + i] = 0;
        // Btf[((ks*8+nf)*64 + l)*8 + j] = W[k][col]
        if (i < 32768) {
            int j  = i & 7;
            int l  = (i >> 3) & 63;
            int nf = (i >> 9) & 7;
            int ks = (i >> 12) & 7;
            int lr = l & 15, kb = l >> 4;
            int col  = nf * 16 + lr;
            int kloc = (ks & 3) * 32 + kb * 8 + j;
            const float* W = (ks < 4) ? Wl : Wr;
            Btf[i] = f2bf(W[kloc * D + col]);
        }
    }
}

// ====== pass B: in-place chunk-prefix (uchar) + PADDED block-local scan =====
// Scans padded degrees (deg+7)&~7 so every node's CSR segment is 8-aligned;
// true degree stored separately for the mean scale.
__global__ __launch_bounds__(256) void scanAB_kernel(uchar* __restrict__ cum,
                                                     int* __restrict__ offsetsP,
                                                     int* __restrict__ blocksums,
                                                     ushort* __restrict__ degArr) {
    __shared__ int wsums[4];
    __shared__ int wbase[4];
    const int t = threadIdx.x;
    const int lane = t & 63;
    const int wid = t >> 6;
    const int n = blockIdx.x * 256 + t;

    int s = 0;
    if (n < N_NODES) {
        #pragma unroll 4
        for (int c = 0; c < NC; ++c) {
            int v = (int)cum[(size_t)c * N_NODES + n];
            cum[(size_t)c * N_NODES + n] = (uchar)s;
            s += v;
        }
        degArr[n] = (ushort)s;
    }
    const int sp = (s + 7) & ~7;          // padded degree
    int sc = sp;
    #pragma unroll
    for (int off = 1; off < 64; off <<= 1) {
        int u = __shfl_up(sc, off);
        if (lane >= off) sc += u;
    }
    if (lane == 63) wsums[wid] = sc;
    __syncthreads();
    if (t == 0) {
        int c = 0;
        #pragma unroll
        for (int w = 0; w < 4; ++w) { int tmp = wsums[w]; wbase[w] = c; c += tmp; }
        blocksums[blockIdx.x] = c;
    }
    __syncthreads();
    if (n < N_NODES) offsetsP[n] = wbase[wid] + sc - sp;
}

// ====== pass C: scatter into CSR (uchar LDS ranks + PARALLEL base scan) =====
__global__ __launch_bounds__(1024) void scatterC_kernel(const int* __restrict__ src,
                                                        const int* __restrict__ dst,
                                                        const int* __restrict__ offsetsP,
                                                        const int* __restrict__ blocksums,
                                                        const uchar* __restrict__ cum,
                                                        ushort* __restrict__ sorted_src,
                                                        int E, int chunk) {
    __shared__ uint cnt[N_NODES / 4];     // 50 KB
    __shared__ int base[SCANB];
    __shared__ int wtot[4];
    const int t = threadIdx.x;
    const int b = blockIdx.x;
    for (int k = t; k < N_NODES / 4; k += 1024) cnt[k] = 0;
    scan_base(blocksums, base, wtot);     // includes barriers
    const uchar* cb = cum + (size_t)b * N_NODES;
    const int e0 = b * chunk;
    const int e1 = min(E, e0 + chunk);
    for (int e = e0 + t; e < e1; e += 1024) {
        int d = dst[e];
        uint prev = atomicAdd(&cnt[d >> 2], 1u << ((d & 3) << 3));
        int lrank = (int)((prev >> ((d & 3) << 3)) & 0xFFu);
        int pos = offsetsP[d] + base[d >> 8] + (int)cb[d] + lrank;
        sorted_src[pos] = (ushort)src[e];
    }
}

// ====== aligned-segment aggregation (fp8 gather) -> bf16 ====================
// Node segments are 8-aligned and 8-padded (pads -> zero row ZROW), so the
// 8-edge loop loads its indices as ONE uint4 (16B aligned) and has no tail.
// 16 lanes/node, one uint2 (8 fp8) of the 128B row each.
__global__ __launch_bounds__(256) void aggregate_fp8(const int* __restrict__ x_fp8,
                                                     const ushort* __restrict__ sorted_src,
                                                     const int* __restrict__ offsetsP,
                                                     const int* __restrict__ blocksums,
                                                     const ushort* __restrict__ degArr,
                                                     ushort* __restrict__ agg_bf) {
    __shared__ int base[SCANB];
    __shared__ int wtot[4];
    const int b = blockIdx.x;
    const int t = threadIdx.x;

    scan_base(blocksums, base, wtot);     // includes barriers

    const int g = t >> 4;                 // node slot 0..15
    const int j = t & 15;                 // uint2 chunk within 128B row
    const int node = b * 16 + g;
    if (node >= N_NODES) return;
    const int dg = (int)degArr[node];
    const int s = offsetsP[node] + base[node >> 8];   // multiple of 8
    const int npad = (dg + 7) & ~7;

    const uint2* xq = (const uint2*)x_fp8;   // row = 16 uint2 (128 fp8)

    float a[8];
    #pragma unroll
    for (int k = 0; k < 8; ++k) a[k] = 0.0f;

    const int pend = s + npad;
    for (int p = s; p < pend; p += 8) {
        uint4 qi = *(const uint4*)&sorted_src[p];     // 8 indices in one load
        int s0 = qi.x & 0xFFFF, s1 = qi.x >> 16;
        int s2 = qi.y & 0xFFFF, s3 = qi.y >> 16;
        int s4 = qi.z & 0xFFFF, s5 = qi.z >> 16;
        int s6 = qi.w & 0xFFFF, s7 = qi.w >> 16;
        uint2 q0 = xq[s0 * 16 + j];
        uint2 q1 = xq[s1 * 16 + j];
        uint2 q2 = xq[s2 * 16 + j];
        uint2 q3 = xq[s3 * 16 + j];
        uint2 q4 = xq[s4 * 16 + j];
        uint2 q5 = xq[s5 * 16 + j];
        uint2 q6 = xq[s6 * 16 + j];
        uint2 q7 = xq[s7 * 16 + j];
        addrow8(q0, a); addrow8(q1, a); addrow8(q2, a); addrow8(q3, a);
        addrow8(q4, a); addrow8(q5, a); addrow8(q6, a); addrow8(q7, a);
    }

    const float scale = (dg > 0) ? (1.0f / (float)dg) : 0.0f;
    ushort tmp[8];
    #pragma unroll
    for (int k = 0; k < 8; ++k) tmp[k] = f2bf(a[k] * scale);
    *(int4*)&agg_bf[node * D + j * 8] = *(int4*)tmp;
}

// ---------------- GEMM, 0 LDS, 0 barriers: out=relu([agg|x]@[Wl;Wr]+b) -----
__global__ __launch_bounds__(256) void gemm_direct(const ushort* __restrict__ agg_bf,
                                                   const ushort* __restrict__ x_bf,
                                                   const ushort* __restrict__ Btf,
                                                   const float* __restrict__ bias,
                                                   float* __restrict__ out) {
    const int t = threadIdx.x;
    const int w = t >> 6;
    const int l = t & 63;
    const int lr = l & 15;
    const int kb = l >> 4;
    const int n0 = blockIdx.x * 64;

    int r = n0 + w * 16 + lr;
    if (r >= N_NODES) r = N_NODES - 1;

    f32x4 acc[8] = {};

    #pragma unroll
    for (int ks = 0; ks < 8; ++ks) {
        bf16x8 af = (ks < 4)
            ? *(const bf16x8*)&agg_bf[r * D + ks * 32 + kb * 8]
            : *(const bf16x8*)&x_bf[r * D + (ks - 4) * 32 + kb * 8];
        const ushort* bp = Btf + (size_t)(ks * 8 * 64 + l) * 8;
        #pragma unroll
        for (int nf = 0; nf < 8; ++nf) {
            bf16x8 bfr = *(const bf16x8*)&bp[nf * 64 * 8];
            acc[nf] = __builtin_amdgcn_mfma_f32_16x16x32_bf16(af, bfr, acc[nf], 0, 0, 0);
        }
    }

    // C/D layout: col = lane&15, row = (lane>>4)*4 + i
    #pragma unroll
    for (int nf = 0; nf < 8; ++nf) {
        const int col = nf * 16 + lr;
        const float bb = bias[col];
        #pragma unroll
        for (int i = 0; i < 4; ++i) {
            int row = n0 + w * 16 + kb * 4 + i;
            if (row < N_NODES)
                out[row * D + col] = fmaxf(acc[nf][i] + bb, 0.0f);
        }
    }
}

// ============================================================================
extern "C" void kernel_launch(void* const* d_in, const int* in_sizes, int n_in,
                              void* d_out, int out_size, void* d_ws, size_t ws_size,
                              hipStream_t stream) {
    const float* x  = (const float*)d_in[0];
    const int*   ei = (const int*)d_in[1];
    const float* Wl = (const float*)d_in[2];
    const float* Wr = (const float*)d_in[3];
    const float* b  = (const float*)d_in[4];
    float* out = (float*)d_out;

    const int E = in_sizes[1] / 2;
    const int* src = ei;
    const int* dst = ei + E;
    const int chunk = (E + NC - 1) / NC;

    // workspace layout (16B-aligned sections)
    char* wsp = (char*)d_ws;
    int*    offsetsP  = (int*)(wsp + 0);               // 50176 ints (padded, local)
    int*    blocksums = (int*)(wsp + 200704);          // 256 ints
    ushort* degArr    = (ushort*)(wsp + 201728);       // 50016 ushorts
    ushort* sorted    = (ushort*)(wsp + 301760);       // 1,200,016 ushorts (2.4MB)
    uchar*  cum       = (uchar*)(wsp + 2701792);       // 256*50000 uchars (12.8MB)
    ushort* x_bf      = (ushort*)(wsp + 15501792);     // 6,400,000 ushorts
    int*    x_fp8     = (int*)(wsp + 28301792);        // 1,600,032 ints (incl. zero row)
    ushort* agg_bf    = (ushort*)(wsp + 34701920);     // 6,400,000 ushorts
    ushort* Btf       = (ushort*)(wsp + 47501920);     // 32768 ushorts
    // total = 47,567,456 bytes

    fused_count_convert<<<NC + CONV_NB, 1024, 0, stream>>>(
        x, Wl, Wr, dst, x_bf, x_fp8, Btf, cum, (uint*)sorted, E, chunk);
    scanAB_kernel<<<SCANB, 256, 0, stream>>>(cum, offsetsP, blocksums, degArr);
    scatterC_kernel<<<NC, 1024, 0, stream>>>(src, dst, offsetsP, blocksums, cum,
                                             sorted, E, chunk);
    aggregate_fp8<<<(N_NODES + 15) / 16, 256, 0, stream>>>(
        x_fp8, sorted, offsetsP, blocksums, degArr, agg_bf);
    gemm_direct<<<(N_NODES + 63) / 64, 256, 0, stream>>>(agg_bf, x_bf, Btf, b, out);
}